// Round 1
// baseline (139.622 us; speedup 1.0000x reference)
//
#include <hip/hip_runtime.h>
#include <math.h>

#define N_EMBED 8192
#define DIM 32
#define NQ 32768              // 32*32*32 queries

#define QPB 512               // queries per block (8 waves x 64)
#define NQG (NQ / QPB)        // 64 query groups
#define KSPL 8                // R6: 16->8. ws: keys16 4MiB->2MiB (total 2.03MiB,
                              // safe vs any ws_size); halves dup A-norm work;
                              // grid 512 = exactly 2 blocks/CU, no tail.
#define KCHUNK (N_EMBED / KSPL)   // 1024 codes per block
#define TILE 128              // codes per LDS tile
#define NTILES (KCHUNK / TILE)    // 8
#define NPLANE 8              // p = s*4 + part ; s=0: h, s=1: m' = (x-h)*4096
#define LSTRIDE 130           // chunks per plane in LDS (+2 pad: planes offset 8 banks)

#define LOSS_OFF  1048576
#define ENT_OFF   1048577
#define IDX_OFF   1048578

typedef __attribute__((ext_vector_type(8))) _Float16 half8;
typedef __attribute__((ext_vector_type(4))) float floatx4;

// ---------------------------------------------------------------------------
// K1: split-fp16 MFMA scorer, 16x16x32, 3 terms: dot = hh + 2^-12(hm' + m'h)
// (exact-split residual; error ~1e-8 rms << fp32 accum noise).
// 512-thread blocks (8 waves -> 16 waves/CU resident).
// NO prep kernel: each block normalizes+splits its own 1024-code chunk inline
// while staging raw e into LDS. Block 0 zeroes usage/loss/done (finalize is
// stream-ordered after ALL score blocks, so no race). One barrier per K-tile.
// Top-1 per (query, chunk) -> keys16[kc*NQ+q].
//
// R6 HARDENING: the prior version failed the post-timing determinism check on
// idx only (near-tie argmax flips) — consistent with finalize reading stale
// keys16 lines after the harness's workspace poison. ALL cross-kernel ws
// state (keys16, usage, loss_acc, done_ctr) now goes through agent-scope
// relaxed atomics so the score->finalize handoff meets at the device-coherent
// point on the 8-XCD part. Traffic is ~4 MiB total -> sub-us cost.
// ---------------------------------------------------------------------------
__global__ __launch_bounds__(512, 4) void score_kernel(const float* __restrict__ z,
                                                       const float* __restrict__ e,
                                                       unsigned long long* __restrict__ keys16,
                                                       unsigned* __restrict__ usage,
                                                       float* __restrict__ loss_acc,
                                                       unsigned* __restrict__ done_ctr) {
    __shared__ half8 lds[2][NPLANE * LSTRIDE];   // 33,280 B

    const int t = threadIdx.x;

    if (blockIdx.x == 0) {           // zero side accumulators for finalize
        for (int i = t; i < N_EMBED; i += 512)
            __hip_atomic_store(&usage[i], 0u, __ATOMIC_RELAXED, __HIP_MEMORY_SCOPE_AGENT);
        if (t == 0) {
            __hip_atomic_store(loss_acc, 0.f, __ATOMIC_RELAXED, __HIP_MEMORY_SCOPE_AGENT);
            __hip_atomic_store(done_ctr, 0u, __ATOMIC_RELAXED, __HIP_MEMORY_SCOPE_AGENT);
        }
    }

    const int lane = t & 63;
    const int w = t >> 6;            // wave 0..7
    const int quad = lane >> 4;      // k-group / C-row group
    const int lc = lane & 15;        // A-row / B-col / C-col
    const int qg = blockIdx.x & (NQG - 1);
    const int kc = blockIdx.x >> 6;          // 0..KSPL-1
    const int kbase = kc * KCHUNK;
    const int qbase = qg * QPB + w * 64;

    // ---- A fragments: 4 q-tiles of 16 rows, normalize + fp16 split ----
    half8 ah[4], am[4];
#pragma unroll
    for (int qt = 0; qt < 4; ++qt) {
        int q = qbase + qt * 16 + lc;
        const float* zp = z + (q >> 10) * (DIM * 1024) + (q & 1023);
        float x[8];
        float ss = 0.f;
#pragma unroll
        for (int j = 0; j < 8; ++j) {
            x[j] = zp[(quad * 8 + j) * 1024];
            ss = fmaf(x[j], x[j], ss);
        }
        ss += __shfl_xor(ss, 16, 64);   // combine the 4 quads holding this query
        ss += __shfl_xor(ss, 32, 64);
        float inv = 1.f / fmaxf(sqrtf(ss), 1e-12f);
#pragma unroll
        for (int j = 0; j < 8; ++j) {
            float xx = x[j] * inv;
            _Float16 h = (_Float16)xx;                           // RNE
            _Float16 m = (_Float16)((xx - (float)h) * 4096.0f);  // exact residual
            ah[qt][j] = h; am[qt][j] = m;
        }
    }

    // ---- stage: 128 codes/tile; 4 threads per code (one 8-dim part each),
    //      load raw e coalesced (32 B/thread), norm via 4-lane shfl, split,
    //      write h-plane (part) and m-plane (4+part) chunks to LDS.
    auto stage = [&](int bsel, int kt) {
        const int ci = t >> 2;           // code within tile, 0..127
        const int part = t & 3;          // 8-dim slice
        const int code = kbase + kt * TILE + ci;
        const float4* er = (const float4*)(e + code * DIM) + part * 2;
        float4 v0 = er[0], v1 = er[1];
        float x[8] = {v0.x, v0.y, v0.z, v0.w, v1.x, v1.y, v1.z, v1.w};
        float ss = 0.f;
#pragma unroll
        for (int j = 0; j < 8; ++j) ss = fmaf(x[j], x[j], ss);
        ss += __shfl_xor(ss, 1, 64);     // sum the 4 parts of this code
        ss += __shfl_xor(ss, 2, 64);
        float inv = 1.f / fmaxf(sqrtf(ss), 1e-12f);
        half8 h8, m8;
#pragma unroll
        for (int j = 0; j < 8; ++j) {
            float xx = x[j] * inv;
            _Float16 h = (_Float16)xx;
            _Float16 m = (_Float16)((xx - (float)h) * 4096.0f);
            h8[j] = h; m8[j] = m;
        }
        lds[bsel][part * LSTRIDE + ci] = h8;
        lds[bsel][(4 + part) * LSTRIDE + ci] = m8;
    };

    float best[16];
    int bk[16];
#pragma unroll
    for (int i = 0; i < 16; ++i) { best[i] = -2.0f; bk[i] = 0; }

    const floatx4 z4 = {0.f, 0.f, 0.f, 0.f};

    stage(0, 0);
    __syncthreads();

    for (int kt = 0; kt < NTILES; ++kt) {
        if (kt + 1 < NTILES) stage((kt + 1) & 1, kt + 1);   // buffer freed by last barrier

        const half8* __restrict__ buf = lds[kt & 1];
#pragma unroll 2
        for (int ct = 0; ct < TILE / 16; ++ct) {
            half8 bh = buf[(0 * 4 + quad) * LSTRIDE + ct * 16 + lc];
            half8 bm = buf[(1 * 4 + quad) * LSTRIDE + ct * 16 + lc];
            const int kk = kbase + kt * TILE + ct * 16 + lc;
#pragma unroll
            for (int qt = 0; qt < 4; ++qt) {
                floatx4 a0 = __builtin_amdgcn_mfma_f32_16x16x32_f16(ah[qt], bh, z4, 0, 0, 0);
                floatx4 a1 = __builtin_amdgcn_mfma_f32_16x16x32_f16(ah[qt], bm, z4, 0, 0, 0);
                a1 = __builtin_amdgcn_mfma_f32_16x16x32_f16(am[qt], bh, a1, 0, 0, 0);
#pragma unroll
                for (int r = 0; r < 4; ++r) {
                    float d = fmaf(a1[r], 0x1p-12f, a0[r]);
                    if (d > best[qt * 4 + r]) { best[qt * 4 + r] = d; bk[qt * 4 + r] = kk; }
                }
            }
        }
        __syncthreads();   // staged tile visible; computed buffer safe to overwrite
    }

    // ---- epilogue: pack (dot,k), reduce over 16 cols, coherent store per row ----
#pragma unroll
    for (int i = 0; i < 16; ++i) {
        unsigned ub = __float_as_uint(best[i]);
        ub = (ub & 0x80000000u) ? ~ub : (ub | 0x80000000u);
        unsigned long long key = ((unsigned long long)ub << 32) | (unsigned)(~bk[i]);
#pragma unroll
        for (int msk = 1; msk <= 8; msk <<= 1) {
            unsigned long long o = __shfl_xor(key, msk, 64);
            key = (o > key) ? o : key;
        }
        if (lc == 0) {
            int qt = i >> 2, r = i & 3;
            int q = qbase + qt * 16 + quad * 4 + r;   // C row = quad*4 + reg
            __hip_atomic_store(&keys16[kc * NQ + q], key,
                               __ATOMIC_RELAXED, __HIP_MEMORY_SCOPE_AGENT);
        }
    }
}

// ---------------------------------------------------------------------------
// K2: finalize. Per query: max over the 8 per-chunk keys (coherent loads;
// max = best dot, tie -> smallest idx; dots bitwise-comparable across chunks
// since A/B frags are kc-independent), ONE row gather + local normalize,
// histogram, straight-through out, loss. Last-done block computes scalars.
// ---------------------------------------------------------------------------
__global__ __launch_bounds__(256) void finalize_kernel(const float* __restrict__ z,
                                                       const float* __restrict__ e,
                                                       const unsigned long long* __restrict__ keys16,
                                                       unsigned* __restrict__ usage,
                                                       float* __restrict__ loss_acc,
                                                       unsigned* __restrict__ done_ctr,
                                                       float* __restrict__ out) {
    int n = blockIdx.x * 256 + threadIdx.x;        // 0..NQ-1
    int b  = n >> 10;
    int hw = n & 1023;
    const float* zb = z + b * (DIM * 1024) + hw;

    float q[DIM];
    float ss = 0.f;
#pragma unroll
    for (int d = 0; d < DIM; ++d) {
        q[d] = zb[d * 1024];
        ss = fmaf(q[d], q[d], ss);
    }
    float inv = 1.f / fmaxf(sqrtf(ss), 1e-12f);
#pragma unroll
    for (int d = 0; d < DIM; ++d) q[d] *= inv;

    unsigned long long bestkey = 0ull;
#pragma unroll
    for (int c = 0; c < KSPL; ++c) {
        unsigned long long k16 = __hip_atomic_load(&keys16[c * NQ + n],
                                                   __ATOMIC_RELAXED,
                                                   __HIP_MEMORY_SCOPE_AGENT);
        bestkey = (k16 > bestkey) ? k16 : bestkey;
    }
    int idx = (int)(~(unsigned)(bestkey & 0xFFFFFFFFull));

    atomicAdd(&usage[idx], 1u);

    // gather winner row, normalize locally, write straight-through + loss
    float wv[DIM];
    float ss2 = 0.f;
    const float4* er = (const float4*)(e + idx * DIM);
#pragma unroll
    for (int d8 = 0; d8 < 8; ++d8) {
        float4 t4 = er[d8];
        wv[d8*4+0] = t4.x; wv[d8*4+1] = t4.y; wv[d8*4+2] = t4.z; wv[d8*4+3] = t4.w;
        ss2 += t4.x*t4.x + t4.y*t4.y + t4.z*t4.z + t4.w*t4.w;
    }
    float inv2 = 1.f / fmaxf(sqrtf(ss2), 1e-12f);

    float lsum = 0.f;
    float* outb = out + b * (DIM * 1024) + hw;
#pragma unroll
    for (int d = 0; d < DIM; ++d) {
        float zq = wv[d] * inv2;
        float diff = zq - q[d];
        lsum = fmaf(diff, diff, lsum);
        outb[d * 1024] = q[d] + (zq - q[d]);   // faithful to zn + sg(z_q - zn)
    }
    out[IDX_OFF + n] = (float)idx;

#pragma unroll
    for (int off = 32; off > 0; off >>= 1)
        lsum += __shfl_down(lsum, off, 64);
    if ((threadIdx.x & 63) == 0)
        atomicAdd(loss_acc, lsum);

    // ---- last-done block computes the scalars ----
    __shared__ unsigned lastflag;
    __syncthreads();
    if (threadIdx.x == 0) {
        __threadfence();
        unsigned prev = __hip_atomic_fetch_add(done_ctr, 1u, __ATOMIC_ACQ_REL,
                                               __HIP_MEMORY_SCOPE_AGENT);
        lastflag = (prev == gridDim.x - 1) ? 1u : 0u;
    }
    __syncthreads();
    if (lastflag) {
        __shared__ double sm[256];
        int t = threadIdx.x;
        double local = 0.0;
        const float denom = 32768.8192f;   // sum(usage)+K*eps; sum(usage)==NQ
        for (int k = t; k < N_EMBED; k += 256) {
            unsigned c = __hip_atomic_load(&usage[k], __ATOMIC_RELAXED,
                                           __HIP_MEMORY_SCOPE_AGENT);
            float p = ((float)c + 1e-4f) / denom;
            local += (double)(-(p * logf(p)));
        }
        sm[t] = local;
        __syncthreads();
        for (int s = 128; s > 0; s >>= 1) {
            if (t < s) sm[t] += sm[t + s];
            __syncthreads();
        }
        if (t == 0) {
            float la = __hip_atomic_load(loss_acc, __ATOMIC_RELAXED,
                                         __HIP_MEMORY_SCOPE_AGENT);
            out[LOSS_OFF] = (float)(1.25 * (double)la / 32768.0);  // (beta+1)*mean
            out[ENT_OFF]  = (float)sm[0];
        }
    }
}

// ---------------------------------------------------------------------------
extern "C" void kernel_launch(void* const* d_in, const int* in_sizes, int n_in,
                              void* d_out, int out_size, void* d_ws, size_t ws_size,
                              hipStream_t stream) {
    const float* z   = (const float*)d_in[0];   // (32, 32, 32, 32) bchw
    const float* emb = (const float*)d_in[1];   // (8192, 32)
    float* out = (float*)d_out;

    char* ws = (char*)d_ws;
    unsigned long long* keys16 = (unsigned long long*)ws;                    // 2 MiB @ 0
    unsigned* usage            = (unsigned*)(ws + (2 << 20));                // 32 KiB
    float* loss_acc            = (float*)(ws + (2 << 20) + 32768);
    unsigned* done_ctr         = (unsigned*)(ws + (2 << 20) + 32768 + 4);

    score_kernel<<<NQG * KSPL, 512, 0, stream>>>(z, emb, keys16, usage,
                                                 loss_acc, done_ctr);
    finalize_kernel<<<NQ / 256, 256, 0, stream>>>(z, emb, keys16, usage,
                                                  loss_acc, done_ctr, out);
}

// Round 2
// 133.063 us; speedup vs baseline: 1.0493x; 1.0493x over previous
//
#include <hip/hip_runtime.h>
#include <math.h>

#define N_EMBED 8192
#define DIM 32
#define NQ 32768              // 32*32*32 queries

#define QPB 512               // queries per block (8 waves x 64)
#define NQG (NQ / QPB)        // 64 query groups
#define KSPL 8                // keys16 2MiB (total ws 2.03MiB); grid 512 = 2 blocks/CU
#define KCHUNK (N_EMBED / KSPL)   // 1024 codes per block
#define TILE 128              // codes per LDS tile
#define NTILES (KCHUNK / TILE)    // 8
#define NPLANE 8              // p = s*4 + part ; s=0: h, s=1: m' = (x-h)*4096
#define LSTRIDE 130           // chunks per plane in LDS (+2 pad: planes offset 8 banks)

#define LOSS_OFF  1048576
#define ENT_OFF   1048577
#define IDX_OFF   1048578

typedef __attribute__((ext_vector_type(8))) _Float16 half8;
typedef __attribute__((ext_vector_type(4))) float floatx4;

// ---------------------------------------------------------------------------
// K1: split-fp16 MFMA scorer, 16x16x32, 3 terms: dot = hh + 2^-12(hm' + m'h)
// (exact-split residual; error ~1e-8 rms << fp32 accum noise).
// 512-thread blocks (8 waves -> 16 waves/CU resident).
// Each block normalizes+splits its own 1024-code chunk inline while staging
// raw e into LDS. Block 0 zeroes usage/loss (finalize is stream-ordered
// after ALL score blocks, so no race). One barrier per K-tile.
// Top-1 per (query, chunk) -> keys16[kc*NQ+q] via agent-scope relaxed atomic
// (cross-kernel handoff hardening from R6 — kept, it's per-access cheap).
// UNCHANGED from R7's passing version for clean attribution.
// ---------------------------------------------------------------------------
__global__ __launch_bounds__(512, 4) void score_kernel(const float* __restrict__ z,
                                                       const float* __restrict__ e,
                                                       unsigned long long* __restrict__ keys16,
                                                       unsigned* __restrict__ usage,
                                                       float* __restrict__ loss_acc) {
    __shared__ half8 lds[2][NPLANE * LSTRIDE];   // 33,280 B

    const int t = threadIdx.x;

    if (blockIdx.x == 0) {           // zero side accumulators for finalize
        for (int i = t; i < N_EMBED; i += 512)
            __hip_atomic_store(&usage[i], 0u, __ATOMIC_RELAXED, __HIP_MEMORY_SCOPE_AGENT);
        if (t == 0)
            __hip_atomic_store(loss_acc, 0.f, __ATOMIC_RELAXED, __HIP_MEMORY_SCOPE_AGENT);
    }

    const int lane = t & 63;
    const int w = t >> 6;            // wave 0..7
    const int quad = lane >> 4;      // k-group / C-row group
    const int lc = lane & 15;        // A-row / B-col / C-col
    const int qg = blockIdx.x & (NQG - 1);
    const int kc = blockIdx.x >> 6;          // 0..KSPL-1
    const int kbase = kc * KCHUNK;
    const int qbase = qg * QPB + w * 64;

    // ---- A fragments: 4 q-tiles of 16 rows, normalize + fp16 split ----
    half8 ah[4], am[4];
#pragma unroll
    for (int qt = 0; qt < 4; ++qt) {
        int q = qbase + qt * 16 + lc;
        const float* zp = z + (q >> 10) * (DIM * 1024) + (q & 1023);
        float x[8];
        float ss = 0.f;
#pragma unroll
        for (int j = 0; j < 8; ++j) {
            x[j] = zp[(quad * 8 + j) * 1024];
            ss = fmaf(x[j], x[j], ss);
        }
        ss += __shfl_xor(ss, 16, 64);   // combine the 4 quads holding this query
        ss += __shfl_xor(ss, 32, 64);
        float inv = 1.f / fmaxf(sqrtf(ss), 1e-12f);
#pragma unroll
        for (int j = 0; j < 8; ++j) {
            float xx = x[j] * inv;
            _Float16 h = (_Float16)xx;                           // RNE
            _Float16 m = (_Float16)((xx - (float)h) * 4096.0f);  // exact residual
            ah[qt][j] = h; am[qt][j] = m;
        }
    }

    // ---- stage: 128 codes/tile; 4 threads per code (one 8-dim part each),
    //      load raw e coalesced (32 B/thread), norm via 4-lane shfl, split,
    //      write h-plane (part) and m-plane (4+part) chunks to LDS.
    auto stage = [&](int bsel, int kt) {
        const int ci = t >> 2;           // code within tile, 0..127
        const int part = t & 3;          // 8-dim slice
        const int code = kbase + kt * TILE + ci;
        const float4* er = (const float4*)(e + code * DIM) + part * 2;
        float4 v0 = er[0], v1 = er[1];
        float x[8] = {v0.x, v0.y, v0.z, v0.w, v1.x, v1.y, v1.z, v1.w};
        float ss = 0.f;
#pragma unroll
        for (int j = 0; j < 8; ++j) ss = fmaf(x[j], x[j], ss);
        ss += __shfl_xor(ss, 1, 64);     // sum the 4 parts of this code
        ss += __shfl_xor(ss, 2, 64);
        float inv = 1.f / fmaxf(sqrtf(ss), 1e-12f);
        half8 h8, m8;
#pragma unroll
        for (int j = 0; j < 8; ++j) {
            float xx = x[j] * inv;
            _Float16 h = (_Float16)xx;
            _Float16 m = (_Float16)((xx - (float)h) * 4096.0f);
            h8[j] = h; m8[j] = m;
        }
        lds[bsel][part * LSTRIDE + ci] = h8;
        lds[bsel][(4 + part) * LSTRIDE + ci] = m8;
    };

    float best[16];
    int bk[16];
#pragma unroll
    for (int i = 0; i < 16; ++i) { best[i] = -2.0f; bk[i] = 0; }

    const floatx4 z4 = {0.f, 0.f, 0.f, 0.f};

    stage(0, 0);
    __syncthreads();

    for (int kt = 0; kt < NTILES; ++kt) {
        if (kt + 1 < NTILES) stage((kt + 1) & 1, kt + 1);   // buffer freed by last barrier

        const half8* __restrict__ buf = lds[kt & 1];
#pragma unroll 2
        for (int ct = 0; ct < TILE / 16; ++ct) {
            half8 bh = buf[(0 * 4 + quad) * LSTRIDE + ct * 16 + lc];
            half8 bm = buf[(1 * 4 + quad) * LSTRIDE + ct * 16 + lc];
            const int kk = kbase + kt * TILE + ct * 16 + lc;
#pragma unroll
            for (int qt = 0; qt < 4; ++qt) {
                floatx4 a0 = __builtin_amdgcn_mfma_f32_16x16x32_f16(ah[qt], bh, z4, 0, 0, 0);
                floatx4 a1 = __builtin_amdgcn_mfma_f32_16x16x32_f16(ah[qt], bm, z4, 0, 0, 0);
                a1 = __builtin_amdgcn_mfma_f32_16x16x32_f16(am[qt], bh, a1, 0, 0, 0);
#pragma unroll
                for (int r = 0; r < 4; ++r) {
                    float d = fmaf(a1[r], 0x1p-12f, a0[r]);
                    if (d > best[qt * 4 + r]) { best[qt * 4 + r] = d; bk[qt * 4 + r] = kk; }
                }
            }
        }
        __syncthreads();   // staged tile visible; computed buffer safe to overwrite
    }

    // ---- epilogue: pack (dot,k), reduce over 16 cols, coherent store per row ----
#pragma unroll
    for (int i = 0; i < 16; ++i) {
        unsigned ub = __float_as_uint(best[i]);
        ub = (ub & 0x80000000u) ? ~ub : (ub | 0x80000000u);
        unsigned long long key = ((unsigned long long)ub << 32) | (unsigned)(~bk[i]);
#pragma unroll
        for (int msk = 1; msk <= 8; msk <<= 1) {
            unsigned long long o = __shfl_xor(key, msk, 64);
            key = (o > key) ? o : key;
        }
        if (lc == 0) {
            int qt = i >> 2, r = i & 3;
            int q = qbase + qt * 16 + quad * 4 + r;   // C row = quad*4 + reg
            __hip_atomic_store(&keys16[kc * NQ + q], key,
                               __ATOMIC_RELAXED, __HIP_MEMORY_SCOPE_AGENT);
        }
    }
}

// ---------------------------------------------------------------------------
// K2: finalize. Per query: max over the 8 per-chunk keys, ONE row gather +
// local normalize, histogram, straight-through out, loss.
// R8: NO __threadfence, NO done_ctr ACQ_REL RMW, NO last-done block — the
// scalar pass moved to a stream-ordered 1-block kernel. Loss reduced
// per-block in LDS -> one atomicAdd per block (256 total, was 512 per-wave).
// 256 blocks x 128 threads fills all CUs.
// ---------------------------------------------------------------------------
__global__ __launch_bounds__(128) void finalize_kernel(const float* __restrict__ z,
                                                       const float* __restrict__ e,
                                                       const unsigned long long* __restrict__ keys16,
                                                       unsigned* __restrict__ usage,
                                                       float* __restrict__ loss_acc,
                                                       float* __restrict__ out) {
    int n = blockIdx.x * 128 + threadIdx.x;        // 0..NQ-1
    int b  = n >> 10;
    int hw = n & 1023;
    const float* zb = z + b * (DIM * 1024) + hw;

    float q[DIM];
    float ss = 0.f;
#pragma unroll
    for (int d = 0; d < DIM; ++d) {
        q[d] = zb[d * 1024];
        ss = fmaf(q[d], q[d], ss);
    }
    float inv = 1.f / fmaxf(sqrtf(ss), 1e-12f);
#pragma unroll
    for (int d = 0; d < DIM; ++d) q[d] *= inv;

    unsigned long long bestkey = 0ull;
#pragma unroll
    for (int c = 0; c < KSPL; ++c) {
        unsigned long long k16 = __hip_atomic_load(&keys16[c * NQ + n],
                                                   __ATOMIC_RELAXED,
                                                   __HIP_MEMORY_SCOPE_AGENT);
        bestkey = (k16 > bestkey) ? k16 : bestkey;
    }
    int idx = (int)(~(unsigned)(bestkey & 0xFFFFFFFFull));

    atomicAdd(&usage[idx], 1u);

    // gather winner row, normalize locally, write straight-through + loss
    float wv[DIM];
    float ss2 = 0.f;
    const float4* er = (const float4*)(e + idx * DIM);
#pragma unroll
    for (int d8 = 0; d8 < 8; ++d8) {
        float4 t4 = er[d8];
        wv[d8*4+0] = t4.x; wv[d8*4+1] = t4.y; wv[d8*4+2] = t4.z; wv[d8*4+3] = t4.w;
        ss2 += t4.x*t4.x + t4.y*t4.y + t4.z*t4.z + t4.w*t4.w;
    }
    float inv2 = 1.f / fmaxf(sqrtf(ss2), 1e-12f);

    float lsum = 0.f;
    float* outb = out + b * (DIM * 1024) + hw;
#pragma unroll
    for (int d = 0; d < DIM; ++d) {
        float zq = wv[d] * inv2;
        float diff = zq - q[d];
        lsum = fmaf(diff, diff, lsum);
        outb[d * 1024] = q[d] + (zq - q[d]);   // faithful to zn + sg(z_q - zn)
    }
    out[IDX_OFF + n] = (float)idx;

    // block-level loss reduction: wave shfl -> LDS -> one atomic per block
#pragma unroll
    for (int off = 32; off > 0; off >>= 1)
        lsum += __shfl_down(lsum, off, 64);
    __shared__ float wsum[2];
    if ((threadIdx.x & 63) == 0) wsum[threadIdx.x >> 6] = lsum;
    __syncthreads();
    if (threadIdx.x == 0)
        atomicAdd(loss_acc, wsum[0] + wsum[1]);
}

// ---------------------------------------------------------------------------
// K3: scalars. Stream-ordered after finalize (kernel boundary = visibility),
// so no fences/counters anywhere. One block, ~3 us.
// ---------------------------------------------------------------------------
__global__ __launch_bounds__(256) void scalar_kernel(const unsigned* __restrict__ usage,
                                                     const float* __restrict__ loss_acc,
                                                     float* __restrict__ out) {
    __shared__ double sm[256];
    int t = threadIdx.x;
    double local = 0.0;
    const float denom = 32768.8192f;   // sum(usage)+K*eps; sum(usage)==NQ
    for (int k = t; k < N_EMBED; k += 256) {
        unsigned c = __hip_atomic_load(&usage[k], __ATOMIC_RELAXED,
                                       __HIP_MEMORY_SCOPE_AGENT);
        float p = ((float)c + 1e-4f) / denom;
        local += (double)(-(p * logf(p)));
    }
    sm[t] = local;
    __syncthreads();
    for (int s = 128; s > 0; s >>= 1) {
        if (t < s) sm[t] += sm[t + s];
        __syncthreads();
    }
    if (t == 0) {
        float la = __hip_atomic_load(loss_acc, __ATOMIC_RELAXED,
                                     __HIP_MEMORY_SCOPE_AGENT);
        out[LOSS_OFF] = (float)(1.25 * (double)la / 32768.0);  // (beta+1)*mean
        out[ENT_OFF]  = (float)sm[0];
    }
}

// ---------------------------------------------------------------------------
extern "C" void kernel_launch(void* const* d_in, const int* in_sizes, int n_in,
                              void* d_out, int out_size, void* d_ws, size_t ws_size,
                              hipStream_t stream) {
    const float* z   = (const float*)d_in[0];   // (32, 32, 32, 32) bchw
    const float* emb = (const float*)d_in[1];   // (8192, 32)
    float* out = (float*)d_out;

    char* ws = (char*)d_ws;
    unsigned long long* keys16 = (unsigned long long*)ws;                    // 2 MiB @ 0
    unsigned* usage            = (unsigned*)(ws + (2 << 20));                // 32 KiB
    float* loss_acc            = (float*)(ws + (2 << 20) + 32768);

    score_kernel<<<NQG * KSPL, 512, 0, stream>>>(z, emb, keys16, usage, loss_acc);
    finalize_kernel<<<NQ / 128, 128, 0, stream>>>(z, emb, keys16, usage,
                                                  loss_acc, out);
    scalar_kernel<<<1, 256, 0, stream>>>(usage, loss_acc, out);
}